// Round 10
// baseline (899.550 us; speedup 1.0000x reference)
//
#include <hip/hip_runtime.h>
#include <cstdint>
#include <cstddef>

#define SS 200
#define NV 100001   // V+1

using int4v = __attribute__((ext_vector_type(4))) int;
using f32x4 = __attribute__((ext_vector_type(4))) float;

__device__ __forceinline__ float sigm(float x){
  return __builtin_amdgcn_rcpf(1.0f + exp2f(x * -1.44269504f));
}
__device__ __forceinline__ int q8(float v, float inv_s){
  float q = rintf(v * inv_s);
  q = fminf(127.f, fmaxf(-127.f, q));
  return (int)q;
}

#define MFI(a,b,c) __builtin_amdgcn_mfma_i32_16x16x64_i8((a),(b),(c),0,0,0)

// LDS-only barrier: orders LDS h/x traffic; leaves global loads in flight.
#define BAR_LDS() do{                                         \
    __builtin_amdgcn_sched_barrier(0);                        \
    asm volatile("s_waitcnt lgkmcnt(0)" ::: "memory");        \
    __builtin_amdgcn_s_barrier();                             \
    __builtin_amdgcn_sched_barrier(0);                        \
  } while(0)

// ---------------- scale: absmax of rec and kernel -> sc[0], sc[1] (float bits) ------
__global__ void scale_kernel(const float* __restrict__ rec,
                             const float* __restrict__ kern,
                             int* __restrict__ sc){
  __shared__ float red[256];
  int tid = threadIdx.x;
  float mr = 0.f, mk = 0.f;
  for (int i = blockIdx.x*256 + tid; i < 262144; i += 256*64) mr = fmaxf(mr, fabsf(rec[i]));
  for (int i = blockIdx.x*256 + tid; i <  65536; i += 256*64) mk = fmaxf(mk, fabsf(kern[i]));
  red[tid] = mr; __syncthreads();
  for (int o = 128; o > 0; o >>= 1){ if (tid < o) red[tid] = fmaxf(red[tid], red[tid+o]); __syncthreads(); }
  if (tid == 0) atomicMax(sc + 0, __float_as_int(red[0]));
  __syncthreads();
  red[tid] = mk; __syncthreads();
  for (int o = 128; o > 0; o >>= 1){ if (tid < o) red[tid] = fmaxf(red[tid], red[tid+o]); __syncthreads(); }
  if (tid == 0) atomicMax(sc + 1, __float_as_int(red[0]));
}

// ---------------- prep: i8 quantized weight frags + per-block tokens + mask bits ----
// rq  : rec i8 A-frags [tile(64)][ktt(4)][lane(64)][j(16)]   tile = w*8+gg*2+hh
// kq  : kern i8 A-frags [tile(64)][lane(64)][j(16)]          (K=64 -> 1 ktt)
// tokB: tokens per lstm-block [blk(64)][s(200)][r(16)]
// maskP: mask bits, 4 x u64 per batch row
__global__ void prep_kernel(const int* __restrict__ inp,
                            const float* __restrict__ kern,
                            const float* __restrict__ rec,
                            const int* __restrict__ sc,
                            char* __restrict__ rq,
                            char* __restrict__ kq,
                            int* __restrict__ tokB,
                            unsigned long long* __restrict__ maskP){
  int idx = blockIdx.x * 256 + threadIdx.x;
  float maxr = __int_as_float(sc[0]);
  float maxk = __int_as_float(sc[1]);
  if (idx < 262144){                    // rec: 256 x 1024, coalesced read
    int k = idx >> 10, col = idx & 1023;
    int gg = col >> 8, w = (col >> 5) & 7, hh = (col >> 4) & 1, l15 = col & 15;
    int tile = w*8 + gg*2 + hh;
    int ktt = k >> 6, hi = (k >> 4) & 3, j = k & 15;
    int lane = l15 + (hi << 4);
    rq[((tile*4 + ktt) << 10) + lane*16 + j] = (char)q8(rec[idx], 127.f/maxr);
  }
  if (idx < 65536){                     // kernel: 64 x 1024
    int k = idx >> 10, col = idx & 1023;
    int gg = col >> 8, w = (col >> 5) & 7, hh = (col >> 4) & 1, l15 = col & 15;
    int tile = w*8 + gg*2 + hh;
    int hi = (k >> 4) & 3, j = k & 15;
    int lane = l15 + (hi << 4);
    kq[(tile << 10) + lane*16 + j] = (char)q8(kern[idx], 127.f/maxk);
  }
  if (idx < 204800){                    // tokens: [blk][s][r]
    int s = idx >> 10, b = idx & 1023;
    int blk = b >> 4, r = b & 15;
    tokB[(blk*SS + s)*16 + r] = inp[b*SS + s];
  }
  if (idx < 4096){                      // mask bit-pack: b = idx>>2, seg = idx&3
    int b = idx >> 2, seg = idx & 3;
    unsigned long long bits = 0ull;
    int base = b * SS + seg * 64;
    int n = (seg < 3) ? 64 : (SS - 192);
    for (int i = 0; i < n; ++i)
      if (inp[base + i] != 0) bits |= (1ull << i);
    maskP[idx] = bits;
  }
}

// ---------------- LSTM: 64 blocks x 1024 thr (16 waves); i8, all-resident -----------
// Round-10 deltas vs round 9:
//  (1) h/x in CANONICAL frag layout (ktt*1024 + lane*16): conflict-free ds_read_b128
//      (stride-272/-80 layouts were 2-way+ conflicted: 4.6M SQ_LDS_BANK_CONFLICT).
//  (2) emb->x pipelined 2 steps deep (x triple-buffer): HBM gather latency (~900cyc,
//      half the rows miss L2) gets a full step of cover instead of sitting on the
//      serial path before each barrier.
//  (3) bias in 16 VGPRs (loaded once from global); biasL LDS deleted (-4 b128/step).
// LDS: h 2x4096 | x 3x1024 | Wx 64K | tok 12.8K = 89600 B
__global__ void __attribute__((amdgpu_flat_work_group_size(1024, 1024),
                               amdgpu_waves_per_eu(4, 4)))
lstm_kernel(const float* __restrict__ emb,
            const float* __restrict__ bias,
            const char* __restrict__ rq,
            const char* __restrict__ kq,
            const int* __restrict__ tokB,
            const unsigned long long* __restrict__ maskP,
            const int* __restrict__ sc,
            float* __restrict__ hout){
  extern __shared__ char smem[];
  char* const hbuf = smem;                    // 2 x 4096
  char* const xbuf = smem + 8192;             // 3 x 1024
  char* const WxL  = smem + 11264;            // 65536
  int*  const tokL = (int*)(smem + 76800);    // 12800
  const int tid  = threadIdx.x;
  const int lane = tid & 63;
  const int wv   = tid >> 6;       // 0..15
  const int w    = wv >> 1;
  const int hh   = wv & 1;
  const int l15  = lane & 15;
  const int l4   = lane >> 4;
  const int blk  = blockIdx.x;
  const int b0   = blk << 4;

  const float maxr = __int_as_float(sc[0]);
  const float maxk = __int_as_float(sc[1]);
  const float S      = maxr * (1.f/16129.f);    // s_rec * s_h
  const float inv_sx = 127.f * maxk / maxr;     // 1/s_x

  // ---- prologue staging ----
  {  // Wx: 64 KB linear
    const int4* src = (const int4*)(kq + tid*64);
    int4* dst = (int4*)(WxL + tid*64);
    #pragma unroll
    for (int q = 0; q < 4; ++q) dst[q] = src[q];
  }
  #pragma unroll
  for (int q = 0; q < 4; ++q){  // tokens: 3200 ints
    int ii = tid + q*1024;
    if (ii < 3200) tokL[ii] = tokB[blk*3200 + ii];
  }
  *(int*)(hbuf + tid*4) = 0;    // zero h parity-0 (4096 B)

  // bias in registers (16 VGPR), loaded once
  f32x4 bv[4];
  #pragma unroll
  for (int gg = 0; gg < 4; ++gg)
    bv[gg] = *(const f32x4*)(bias + gg*256 + w*32 + hh*16 + (l4<<2));

  // resident rec frags: 16 x int4v = 64 VGPR
  int4v Wr[4][4];
  #pragma unroll
  for (int ktt = 0; ktt < 4; ++ktt)
    #pragma unroll
    for (int gg = 0; gg < 4; ++gg)
      Wr[ktt][gg] = *(const int4v*)(rq + ((((w*8 + gg*2+hh)*4 + ktt)) << 10) + (lane << 4));

  // frag-layout addresses
  const int x_wr = (wv << 4) + ((lane >> 4) << 8) + l15;   // byte write in x frag
  const int h_wr = ((w >> 1) << 10)
                 + ((l15 + ((((w & 1) << 1) + hh) << 4)) << 4) + (l4 << 2);

  // x(0), x(1) staged; emb(2) issued into xvP
  {
    int t0 = tokB[blk*3200 + wv];
    float v0 = emb[(size_t)t0 * 64 + lane];
    *(char*)(xbuf + x_wr) = (char)q8(v0, inv_sx);
    int t1 = tokB[blk*3200 + 16 + wv];
    float v1 = emb[(size_t)t1 * 64 + lane];
    *(char*)(xbuf + 1024 + x_wr) = (char)q8(v1, inv_sx);
  }
  float xvP;
  {
    int t2 = tokB[blk*3200 + 32 + wv];
    xvP = emb[(size_t)t2 * 64 + lane];
  }

  const unsigned long long* maskB = maskP + (size_t)(b0 + l15) * 4;
  float c[4]  = {0.f, 0.f, 0.f, 0.f};
  float hr[4] = {0.f, 0.f, 0.f, 0.f};

  __syncthreads();

  int s = 0, xri = 0;   // xri = s % 3
  #pragma unroll 1
  for (int seg = 0; seg < 4; ++seg){
    unsigned long long cur = maskB[seg];
    const int nn = (seg < 3) ? 64 : (SS - 192);
    #pragma unroll 1
    for (int i = 0; i < nn; ++i, ++s){
      const char* hc = hbuf + ((s & 1) << 12);
      char*       hn = hbuf + (((s & 1) ^ 1) << 12);
      const char* xc = xbuf + xri*1024;
      int xwi = xri + 2; if (xwi >= 3) xwi -= 3;
      char*       xw = xbuf + xwi*1024;

      // (2a) write x(s+2) from the register loaded during step s-1
      if (s + 2 < SS) *(char*)(xw + x_wr) = (char)q8(xvP, inv_sx);
      // (2b) issue emb(s+3) -> xvP; a full step to land
      if (s + 3 < SS){
        int tn = tokL[(s+3)*16 + wv];
        xvP = emb[(size_t)tn * 64 + lane];
      }

      // MFMAs: x + 4 rec ktt per gate, shared i32 acc
      int4v acc[4];
      #pragma unroll
      for (int gg = 0; gg < 4; ++gg) acc[gg] = int4v{0,0,0,0};
      {
        int4v xf = *(const int4v*)(xc + (lane << 4));
        #pragma unroll
        for (int gg = 0; gg < 4; ++gg){
          int4v wx = *(const int4v*)(WxL + ((w*8 + gg*2+hh) << 10) + (lane << 4));
          acc[gg] = MFI(wx, xf, acc[gg]);
        }
      }
      #pragma unroll
      for (int ktt = 0; ktt < 4; ++ktt){
        int4v hf = *(const int4v*)(hc + ktt*1024 + (lane << 4));
        #pragma unroll
        for (int gg = 0; gg < 4; ++gg) acc[gg] = MFI(Wr[ktt][gg], hf, acc[gg]);
      }

      // gates: z = bias + S*acc; all-sigmoid LSTM; masked rows keep c,h
      int tkb = (int)(cur & 1ull);
      cur >>= 1;
      #pragma unroll
      for (int r = 0; r < 4; ++r){
        float zi = fmaf(S, (float)acc[0][r], bv[0][r]);
        float zf = fmaf(S, (float)acc[1][r], bv[1][r]);
        float zg = fmaf(S, (float)acc[2][r], bv[2][r]);
        float zo = fmaf(S, (float)acc[3][r], bv[3][r]);
        float si = sigm(zi), sf = sigm(zf), sg = sigm(zg), so = sigm(zo);
        float cn = sf * c[r] + si * sg;
        float hv = so * sigm(cn);
        if (tkb){ c[r] = cn; hr[r] = hv; }
      }
      unsigned int pk = 0u;
      #pragma unroll
      for (int r = 0; r < 4; ++r)
        pk |= ((unsigned int)((int)rintf(hr[r] * 127.f) & 0xff)) << (8*r);
      *(unsigned int*)(hn + h_wr) = pk;

      xri = (xri == 2) ? 0 : xri + 1;
      BAR_LDS();   // LDS-only barrier; emb loads stay in flight
    }
  }

  // final h (fp32)
  *(float4*)(hout + (b0 + l15)*256 + w*32 + hh*16 + (l4<<2)) =
      make_float4(hr[0], hr[1], hr[2], hr[3]);
}

// ---------------- dense: out = h @ dense_w + dense_b  (1024x64, K=256) --------------
__global__ void dense_kernel(const float* __restrict__ h,
                             const float* __restrict__ dw,
                             const float* __restrict__ db,
                             float* __restrict__ outv){
  int tid = threadIdx.x;
  int e = tid & 63;
  int b = blockIdx.x * 4 + (tid >> 6);
  const float* hb = h + b * 256;
  float a = db[e];
  #pragma unroll 8
  for (int u = 0; u < 256; ++u) a = fmaf(hb[u], dw[u*64 + e], a);
  outv[b*64 + e] = a;
}

// ---------------- logits: dst = out @ emb.T  (1024 x 100001, K=64, fp32) ------------
__global__ void __launch_bounds__(256)
logits_kernel(const float* __restrict__ outv,
              const float* __restrict__ emb,
              float* __restrict__ dst){
  int v = blockIdx.x * 256 + threadIdx.x;
  const bool valid = (v < NV);
  const int vs = valid ? v : 0;
  const int bb = blockIdx.y * 256;
  float er[64];
  #pragma unroll
  for (int q = 0; q < 16; ++q){
    float4 tq = *(const float4*)(emb + (size_t)vs * 64 + q*4);
    er[q*4+0] = tq.x; er[q*4+1] = tq.y; er[q*4+2] = tq.z; er[q*4+3] = tq.w;
  }
  for (int b = bb; b < bb + 256; ++b){
    const float* ob = outv + b*64;   // wave-uniform -> scalar loads
    float a0 = 0.f, a1 = 0.f;
    #pragma unroll
    for (int e = 0; e < 64; e += 2){
      a0 = fmaf(ob[e],   er[e],   a0);
      a1 = fmaf(ob[e+1], er[e+1], a1);
    }
    if (valid) dst[(size_t)b * NV + v] = a0 + a1;
  }
}

extern "C" void kernel_launch(void* const* d_in, const int* in_sizes, int n_in,
                              void* d_out, int out_size, void* d_ws, size_t ws_size,
                              hipStream_t stream){
  const int*   inp  = (const int*)  d_in[0];
  const float* emb  = (const float*)d_in[1];
  const float* kern = (const float*)d_in[2];
  const float* rec  = (const float*)d_in[3];
  const float* bias = (const float*)d_in[4];
  const float* dw   = (const float*)d_in[5];
  const float* db   = (const float*)d_in[6];
  float* dst = (float*)d_out;
  char* ws = (char*)d_ws;

  int*                sc    = (int*)               (ws);            // 8 B (+pad)
  char*               rq    = (char*)              (ws + 4096);     // 262144 B
  char*               kq    = (char*)              (ws + 266240);   // 65536 B
  int*                tokB  = (int*)               (ws + 331776);   // 819200 B
  unsigned long long* maskP = (unsigned long long*)(ws + 1150976);  // 32768 B
  float*              hbuf  = (float*)             (ws + 1183744);  // 1048576 B
  float*              obuf  = (float*)             (ws + 2232320);  // 262144 B

  const int SMEM_BYTES = 89600;
  hipFuncSetAttribute((const void*)lstm_kernel,
                      hipFuncAttributeMaxDynamicSharedMemorySize, SMEM_BYTES);

  hipMemsetAsync(sc, 0, 8, stream);
  scale_kernel <<<64, 256, 0, stream>>>(rec, kern, sc);
  prep_kernel  <<<1024, 256, 0, stream>>>(inp, kern, rec, sc, rq, kq, tokB, maskP);
  lstm_kernel  <<<64, 1024, SMEM_BYTES, stream>>>(emb, bias, rq, kq, tokB, maskP, sc, hbuf);
  dense_kernel <<<256, 256, 0, stream>>>(hbuf, dw, db, obuf);
  logits_kernel<<<dim3(391, 4), 256, 0, stream>>>(obuf, emb, dst);
  (void)in_sizes; (void)n_in; (void)out_size; (void)ws_size;
}

// Round 11
// 574.216 us; speedup vs baseline: 1.5666x; 1.5666x over previous
//
#include <hip/hip_runtime.h>
#include <cstdint>
#include <cstddef>

#define SS 200
#define NV 100001   // V+1

using int4v = __attribute__((ext_vector_type(4))) int;
using f32x4 = __attribute__((ext_vector_type(4))) float;

__device__ __forceinline__ int q8(float v, float inv_s){
  float q = rintf(v * inv_s);
  q = fminf(127.f, fmaxf(-127.f, q));
  return (int)q;
}
// sigm with pre-negated-scaled input: sg1(t) = 1/(1+exp2(t)), t = -log2e * z
__device__ __forceinline__ float sg1(float t){
  return __builtin_amdgcn_rcpf(1.0f + exp2f(t));
}

#define MFI(a,b,c) __builtin_amdgcn_mfma_i32_16x16x64_i8((a),(b),(c),0,0,0)

// LDS-only barrier: orders LDS traffic; leaves global loads in flight.
#define BAR_LDS() do{                                         \
    __builtin_amdgcn_sched_barrier(0);                        \
    asm volatile("s_waitcnt lgkmcnt(0)" ::: "memory");        \
    __builtin_amdgcn_s_barrier();                             \
    __builtin_amdgcn_sched_barrier(0);                        \
  } while(0)

// ---------------- scale: absmax of rec and kernel -> sc[0], sc[1] (float bits) ------
__global__ void scale_kernel(const float* __restrict__ rec,
                             const float* __restrict__ kern,
                             int* __restrict__ sc){
  __shared__ float red[256];
  int tid = threadIdx.x;
  float mr = 0.f, mk = 0.f;
  for (int i = blockIdx.x*256 + tid; i < 262144; i += 256*64) mr = fmaxf(mr, fabsf(rec[i]));
  for (int i = blockIdx.x*256 + tid; i <  65536; i += 256*64) mk = fmaxf(mk, fabsf(kern[i]));
  red[tid] = mr; __syncthreads();
  for (int o = 128; o > 0; o >>= 1){ if (tid < o) red[tid] = fmaxf(red[tid], red[tid+o]); __syncthreads(); }
  if (tid == 0) atomicMax(sc + 0, __float_as_int(red[0]));
  __syncthreads();
  red[tid] = mk; __syncthreads();
  for (int o = 128; o > 0; o >>= 1){ if (tid < o) red[tid] = fmaxf(red[tid], red[tid+o]); __syncthreads(); }
  if (tid == 0) atomicMax(sc + 1, __float_as_int(red[0]));
}

// ---------------- prep: i8 quantized weight frags + per-block tokens + mask bits ----
// rq  : rec i8 A-frags [tile(64)][ktt(4)][lane(64)][j(16)]   tile = w*8+gg*2+hh
// kq  : kern i8 A-frags [tile(64)][lane(64)][j(16)]
// tokB: tokens per lstm-block [blk(128)][s(200)][r(8)]
// maskP: mask bits, 4 x u64 per batch row
__global__ void prep_kernel(const int* __restrict__ inp,
                            const float* __restrict__ kern,
                            const float* __restrict__ rec,
                            const int* __restrict__ sc,
                            char* __restrict__ rq,
                            char* __restrict__ kq,
                            int* __restrict__ tokB,
                            unsigned long long* __restrict__ maskP){
  int idx = blockIdx.x * 256 + threadIdx.x;
  float maxr = __int_as_float(sc[0]);
  float maxk = __int_as_float(sc[1]);
  if (idx < 262144){                    // rec: 256 x 1024, coalesced read
    int k = idx >> 10, col = idx & 1023;
    int gg = col >> 8, w = (col >> 5) & 7, hh = (col >> 4) & 1, l15 = col & 15;
    int tile = w*8 + gg*2 + hh;
    int ktt = k >> 6, hi = (k >> 4) & 3, j = k & 15;
    int lane = l15 + (hi << 4);
    rq[((tile*4 + ktt) << 10) + lane*16 + j] = (char)q8(rec[idx], 127.f/maxr);
  }
  if (idx < 65536){                     // kernel: 64 x 1024
    int k = idx >> 10, col = idx & 1023;
    int gg = col >> 8, w = (col >> 5) & 7, hh = (col >> 4) & 1, l15 = col & 15;
    int tile = w*8 + gg*2 + hh;
    int hi = (k >> 4) & 3, j = k & 15;
    int lane = l15 + (hi << 4);
    kq[(tile << 10) + lane*16 + j] = (char)q8(kern[idx], 127.f/maxk);
  }
  if (idx < 204800){                    // tokens: [blk][s][r], blk = b>>3
    int s = idx >> 10, b = idx & 1023;
    int blk = b >> 3, r = b & 7;
    tokB[(blk*SS + s)*8 + r] = inp[b*SS + s];
  }
  if (idx < 4096){                      // mask bit-pack: b = idx>>2, seg = idx&3
    int b = idx >> 2, seg = idx & 3;
    unsigned long long bits = 0ull;
    int base = b * SS + seg * 64;
    int n = (seg < 3) ? 64 : (SS - 192);
    for (int i = 0; i < n; ++i)
      if (inp[base + i] != 0) bits |= (1ull << i);
    maskP[idx] = bits;
  }
}

// ---------------- LSTM: 128 blocks x 1024 thr (16 waves); 8 batch rows per block ----
// Round-11: gate VALU was the wall (per-active-CU VALUBusy ~62%, 64 CUs). Split batch
// 2x (128 CUs) and re-densify gate lanes: MFMA D cols 0-7 valid (8 batch); lanes
// l15>=8 pull regs {2,3} from lane-8 via ds_bpermute -> every lane owns complete
// i/f/g/o quadruples for 2 (b,u): 10 sigm/thread (was 20). Per-SIMD gate issue
// halves AND CU count doubles. Wx in VGPRs; -log2e folded into scale+bias.
// h frag layout [ktt(4)][kchunk(4)][b(8)][16B] -> conflict-free b128 (pairs bcast).
// LDS: h 2x2048 | x 3x512 | tok 6400 = 12032 B
__global__ void __attribute__((amdgpu_flat_work_group_size(1024, 1024),
                               amdgpu_waves_per_eu(4, 4)))
lstm_kernel(const float* __restrict__ emb,
            const float* __restrict__ bias,
            const char* __restrict__ rq,
            const char* __restrict__ kq,
            const int* __restrict__ tokB,
            const unsigned long long* __restrict__ maskP,
            const int* __restrict__ sc,
            float* __restrict__ hout){
  extern __shared__ char smem[];
  char* const hbuf = smem;                    // 2 x 2048
  char* const xbuf = smem + 4096;             // 3 x 512
  int*  const tokL = (int*)(smem + 5632);     // 6400
  const int tid  = threadIdx.x;
  const int lane = tid & 63;
  const int wv   = tid >> 6;       // 0..15
  const int w    = wv >> 1;
  const int hh   = wv & 1;
  const int l15  = lane & 15;
  const int l4   = lane >> 4;
  const int blk  = blockIdx.x;
  const int b0   = blk << 3;       // 8 batch rows per block
  const int bcol = l15 & 7;
  const bool lo8 = (l15 < 8);
  const int rA   = lo8 ? 0 : 2;
  const int srcb = (((lane & 48) | bcol) << 2);   // bpermute byte addr

  const float maxr = __int_as_float(sc[0]);
  const float maxk = __int_as_float(sc[1]);
  const float S      = maxr * (1.f/16129.f);
  const float SL     = -1.44269504f * S;          // fold -log2e into scale
  const float inv_sx = 127.f * maxk / maxr;

  // ---- prologue staging ----
  #pragma unroll
  for (int q = 0; q < 2; ++q){   // tokens: 1600 ints
    int ii = tid + q*1024;
    if (ii < 1600) tokL[ii] = tokB[blk*1600 + ii];
  }
  if (tid < 512) *(int*)(hbuf + tid*4) = 0;       // zero h parity-0 (2048 B)

  // bias in 8 regs, -log2e-folded: thread's 2 (b,u) x 4 gates
  float bn[4][2];
  {
    int u0 = w*32 + hh*16 + (l4<<2) + rA;
    #pragma unroll
    for (int gg = 0; gg < 4; ++gg){
      bn[gg][0] = -1.44269504f * bias[gg*256 + u0];
      bn[gg][1] = -1.44269504f * bias[gg*256 + u0 + 1];
    }
  }
  // resident rec frags (64 VGPR/AGPR) + kernel frags (16)
  int4v Wr[4][4];
  #pragma unroll
  for (int ktt = 0; ktt < 4; ++ktt)
    #pragma unroll
    for (int gg = 0; gg < 4; ++gg)
      Wr[ktt][gg] = *(const int4v*)(rq + ((((w*8 + gg*2+hh)*4 + ktt)) << 10) + (lane << 4));
  int4v Wx[4];
  #pragma unroll
  for (int gg = 0; gg < 4; ++gg)
    Wx[gg] = *(const int4v*)(kq + ((w*8 + gg*2+hh) << 10) + (lane << 4));

  // x frag layout [kchunk(4)][b(8)][16B]; waves 0-7 stage row wv
  const int x_wr = ((lane >> 4) << 7) + (wv << 4) + (l15 & 15) - ((lane & 15) > 15 ? 0 : 0); // placeholder
  const int x_wrb = ((lane >> 4) << 7) + (wv << 4) + (lane & 15);
  float xvP = 0.f;
  if (wv < 8){
    int t0 = tokL[wv];
    float v0 = emb[(size_t)t0 * 64 + lane];
    *(char*)(xbuf + x_wrb) = (char)q8(v0, inv_sx);
    int t1 = tokL[8 + wv];
    float v1 = emb[(size_t)t1 * 64 + lane];
    *(char*)(xbuf + 512 + x_wrb) = (char)q8(v1, inv_sx);
    int t2 = tokL[16 + wv];
    xvP = emb[(size_t)t2 * 64 + lane];
  }

  const unsigned long long* maskB = maskP + (size_t)(b0 + bcol) * 4;
  float c[2]  = {0.f, 0.f};
  float hPrev[2] = {0.f, 0.f};
  const int f_rd = ((lane >> 4) << 7) + (bcol << 4);       // frag read offset
  const int h_wb = ((w >> 1) << 9) + (((((w & 1) << 1) | hh)) << 7)
                 + (bcol << 4) + (l4 << 2) + rA;           // h u16 write

  __syncthreads();

  int s = 0, xri = 0;
  #pragma unroll 1
  for (int seg = 0; seg < 4; ++seg){
    unsigned long long cur = maskB[seg];
    const int nn = (seg < 3) ? 64 : (SS - 192);
    #pragma unroll 1
    for (int i = 0; i < nn; ++i, ++s){
      const char* hc = hbuf + ((s & 1) << 11);
      char*       hn = hbuf + (((s & 1) ^ 1) << 11);
      const char* xc = xbuf + xri*512;
      int xwi = xri + 2; if (xwi >= 3) xwi -= 3;
      char*       xw = xbuf + xwi*512;

      // stage x(s+2) from register; issue emb(s+3)
      if (wv < 8){
        if (s + 2 < SS) *(char*)(xw + x_wrb) = (char)q8(xvP, inv_sx);
        if (s + 3 < SS){
          int tn = tokL[(s+3)*8 + wv];
          xvP = emb[(size_t)tn * 64 + lane];
        }
      }

      // MFMA: x + 4 rec ktt per gate-tile
      int4v acc[4];
      #pragma unroll
      for (int gg = 0; gg < 4; ++gg) acc[gg] = int4v{0,0,0,0};
      {
        int4v xf = *(const int4v*)(xc + f_rd);
        #pragma unroll
        for (int gg = 0; gg < 4; ++gg) acc[gg] = MFI(Wx[gg], xf, acc[gg]);
      }
      #pragma unroll
      for (int ktt = 0; ktt < 4; ++ktt){
        int4v hf = *(const int4v*)(hc + (ktt << 9) + f_rd);
        #pragma unroll
        for (int gg = 0; gg < 4; ++gg) acc[gg] = MFI(Wr[ktt][gg], hf, acc[gg]);
      }

      // lane-spread: lanes l15>=8 take regs {2,3} of lane-8 -> dense gate work
      float zs[4][2];
      #pragma unroll
      for (int gg = 0; gg < 4; ++gg){
        int t2 = __builtin_amdgcn_ds_bpermute(srcb, acc[gg][2]);
        int t3 = __builtin_amdgcn_ds_bpermute(srcb, acc[gg][3]);
        int zA = lo8 ? acc[gg][0] : t2;
        int zB = lo8 ? acc[gg][1] : t3;
        zs[gg][0] = fmaf(SL, (float)zA, bn[gg][0]);
        zs[gg][1] = fmaf(SL, (float)zB, bn[gg][1]);
      }

      // gates (2 (b,u) per thread, 10 sigm); masked rows keep c,h
      int tkb = (int)(cur & 1ull);
      cur >>= 1;
      #pragma unroll
      for (int p = 0; p < 2; ++p){
        float si = sg1(zs[0][p]);
        float sf = sg1(zs[1][p]);
        float sg = sg1(zs[2][p]);
        float so = sg1(zs[3][p]);
        float cn = fmaf(sf, c[p], si * sg);
        float hv = so * sg1(cn * -1.44269504f);
        if (tkb){ c[p] = cn; hPrev[p] = hv; }
      }
      // pack 2 h -> u16 (h in (0,1): no sign bits)
      int q0 = (int)rintf(hPrev[0] * 127.f);
      int q1 = (int)rintf(hPrev[1] * 127.f);
      *(unsigned short*)(hn + h_wb) = (unsigned short)(q0 | (q1 << 8));

      xri = (xri == 2) ? 0 : xri + 1;
      BAR_LDS();
    }
  }

  // final h (fp32): thread's 2 consecutive u for batch bcol
  {
    int u0 = w*32 + hh*16 + (l4<<2) + rA;
    *(float2*)(hout + (size_t)(b0 + bcol)*256 + u0) = make_float2(hPrev[0], hPrev[1]);
  }
}

// ---------------- dense: out = h @ dense_w + dense_b  (1024x64, K=256) --------------
__global__ void dense_kernel(const float* __restrict__ h,
                             const float* __restrict__ dw,
                             const float* __restrict__ db,
                             float* __restrict__ outv){
  int tid = threadIdx.x;
  int e = tid & 63;
  int b = blockIdx.x * 4 + (tid >> 6);
  const float* hb = h + b * 256;
  float a = db[e];
  #pragma unroll 8
  for (int u = 0; u < 256; ++u) a = fmaf(hb[u], dw[u*64 + e], a);
  outv[b*64 + e] = a;
}

// ---------------- logits: dst = out @ emb.T  (1024 x 100001, K=64, fp32) ------------
__global__ void __launch_bounds__(256)
logits_kernel(const float* __restrict__ outv,
              const float* __restrict__ emb,
              float* __restrict__ dst){
  int v = blockIdx.x * 256 + threadIdx.x;
  const bool valid = (v < NV);
  const int vs = valid ? v : 0;
  const int bb = blockIdx.y * 256;
  float er[64];
  #pragma unroll
  for (int q = 0; q < 16; ++q){
    float4 tq = *(const float4*)(emb + (size_t)vs * 64 + q*4);
    er[q*4+0] = tq.x; er[q*4+1] = tq.y; er[q*4+2] = tq.z; er[q*4+3] = tq.w;
  }
  for (int b = bb; b < bb + 256; ++b){
    const float* ob = outv + b*64;   // wave-uniform -> scalar loads
    float a0 = 0.f, a1 = 0.f;
    #pragma unroll
    for (int e = 0; e < 64; e += 2){
      a0 = fmaf(ob[e],   er[e],   a0);
      a1 = fmaf(ob[e+1], er[e+1], a1);
    }
    if (valid) dst[(size_t)b * NV + v] = a0 + a1;
  }
}

extern "C" void kernel_launch(void* const* d_in, const int* in_sizes, int n_in,
                              void* d_out, int out_size, void* d_ws, size_t ws_size,
                              hipStream_t stream){
  const int*   inp  = (const int*)  d_in[0];
  const float* emb  = (const float*)d_in[1];
  const float* kern = (const float*)d_in[2];
  const float* rec  = (const float*)d_in[3];
  const float* bias = (const float*)d_in[4];
  const float* dw   = (const float*)d_in[5];
  const float* db   = (const float*)d_in[6];
  float* dst = (float*)d_out;
  char* ws = (char*)d_ws;

  int*                sc    = (int*)               (ws);            // 8 B (+pad)
  char*               rq    = (char*)              (ws + 4096);     // 262144 B
  char*               kq    = (char*)              (ws + 266240);   // 65536 B
  int*                tokB  = (int*)               (ws + 331776);   // 819200 B
  unsigned long long* maskP = (unsigned long long*)(ws + 1150976);  // 32768 B
  float*              hbuf  = (float*)             (ws + 1183744);  // 1048576 B
  float*              obuf  = (float*)             (ws + 2232320);  // 262144 B

  const int SMEM_BYTES = 12032;
  hipFuncSetAttribute((const void*)lstm_kernel,
                      hipFuncAttributeMaxDynamicSharedMemorySize, SMEM_BYTES);

  hipMemsetAsync(sc, 0, 8, stream);
  scale_kernel <<<64, 256, 0, stream>>>(rec, kern, sc);
  prep_kernel  <<<1024, 256, 0, stream>>>(inp, kern, rec, sc, rq, kq, tokB, maskP);
  lstm_kernel  <<<128, 1024, SMEM_BYTES, stream>>>(emb, bias, rq, kq, tokB, maskP, sc, hbuf);
  dense_kernel <<<256, 256, 0, stream>>>(hbuf, dw, db, obuf);
  logits_kernel<<<dim3(391, 4), 256, 0, stream>>>(obuf, emb, dst);
  (void)in_sizes; (void)n_in; (void)out_size; (void)ws_size;
}

// Round 12
// 463.042 us; speedup vs baseline: 1.9427x; 1.2401x over previous
//
#include <hip/hip_runtime.h>
#include <cstdint>
#include <cstddef>

#define SS 200
#define NV 100001   // V+1

using int4v  = __attribute__((ext_vector_type(4))) int;
using f32x4  = __attribute__((ext_vector_type(4))) float;
using short8 = __attribute__((ext_vector_type(8))) short;

__device__ __forceinline__ unsigned short f2bf(float f){
  unsigned int x = __float_as_uint(f);
  x += 0x7fffu + ((x >> 16) & 1u);
  return (unsigned short)(x >> 16);
}
__device__ __forceinline__ int q8(float v, float inv_s){
  float q = rintf(v * inv_s);
  q = fminf(127.f, fmaxf(-127.f, q));
  return (int)q;
}
// sg1(t) = 1/(1+exp2(t));  sigmoid(z) = sg1(-log2e * z)
__device__ __forceinline__ float sg1(float t){
  return __builtin_amdgcn_rcpf(1.0f + exp2f(t));
}

#define MFI(a,b,c) __builtin_amdgcn_mfma_i32_16x16x64_i8((a),(b),(c),0,0,0)
#define MFB(a,b,c) __builtin_amdgcn_mfma_f32_16x16x32_bf16((a),(b),(c),0,0,0)

// LDS-only barrier: orders LDS traffic; leaves global loads in flight.
#define BAR_LDS() do{                                         \
    __builtin_amdgcn_sched_barrier(0);                        \
    asm volatile("s_waitcnt lgkmcnt(0)" ::: "memory");        \
    __builtin_amdgcn_s_barrier();                             \
    __builtin_amdgcn_sched_barrier(0);                        \
  } while(0)

// ---------------- scale: absmax of rec and kernel -> sc[0], sc[1] (float bits) ------
__global__ void scale_kernel(const float* __restrict__ rec,
                             const float* __restrict__ kern,
                             int* __restrict__ sc){
  __shared__ float red[256];
  int tid = threadIdx.x;
  float mr = 0.f, mk = 0.f;
  for (int i = blockIdx.x*256 + tid; i < 262144; i += 256*64) mr = fmaxf(mr, fabsf(rec[i]));
  for (int i = blockIdx.x*256 + tid; i <  65536; i += 256*64) mk = fmaxf(mk, fabsf(kern[i]));
  red[tid] = mr; __syncthreads();
  for (int o = 128; o > 0; o >>= 1){ if (tid < o) red[tid] = fmaxf(red[tid], red[tid+o]); __syncthreads(); }
  if (tid == 0) atomicMax(sc + 0, __float_as_int(red[0]));
  __syncthreads();
  red[tid] = mk; __syncthreads();
  for (int o = 128; o > 0; o >>= 1){ if (tid < o) red[tid] = fmaxf(red[tid], red[tid+o]); __syncthreads(); }
  if (tid == 0) atomicMax(sc + 1, __float_as_int(red[0]));
}

// ---------------- prep: i8 weight frags + tokens + mask bits + emb bf16 B-frags -----
// rq  : rec i8 A-frags [tile(64)][ktt(4)][lane(64)][j(16)]
// kq  : kern i8 A-frags [tile(64)][lane(64)][j(16)]
// tokB: tokens per lstm-block [blk(256)][s(200)][r(4)]
// maskP: mask bits, 4 x u64 per batch row
// ebf : emb bf16 B-frags [vt(6252)][kt(2)][lane(64)][j(8)]  (v >= NV zero-padded)
__global__ void prep_kernel(const int* __restrict__ inp,
                            const float* __restrict__ kern,
                            const float* __restrict__ rec,
                            const float* __restrict__ emb,
                            const int* __restrict__ sc,
                            char* __restrict__ rq,
                            char* __restrict__ kq,
                            int* __restrict__ tokB,
                            unsigned long long* __restrict__ maskP,
                            unsigned short* __restrict__ ebf){
  int idx = blockIdx.x * 256 + threadIdx.x;
  float maxr = __int_as_float(sc[0]);
  float maxk = __int_as_float(sc[1]);
  if (idx < 262144){                    // rec: 256 x 1024, coalesced read
    int k = idx >> 10, col = idx & 1023;
    int gg = col >> 8, w = (col >> 5) & 7, hh = (col >> 4) & 1, l15 = col & 15;
    int tile = w*8 + gg*2 + hh;
    int ktt = k >> 6, hi = (k >> 4) & 3, j = k & 15;
    int lane = l15 + (hi << 4);
    rq[((tile*4 + ktt) << 10) + lane*16 + j] = (char)q8(rec[idx], 127.f/maxr);
  }
  if (idx < 65536){                     // kernel: 64 x 1024
    int k = idx >> 10, col = idx & 1023;
    int gg = col >> 8, w = (col >> 5) & 7, hh = (col >> 4) & 1, l15 = col & 15;
    int tile = w*8 + gg*2 + hh;
    int hi = (k >> 4) & 3, j = k & 15;
    int lane = l15 + (hi << 4);
    kq[(tile << 10) + lane*16 + j] = (char)q8(kern[idx], 127.f/maxk);
  }
  if (idx < 204800){                    // tokens: [blk][s][r], blk = b>>2
    int s = idx >> 10, b = idx & 1023;
    int blk = b >> 2, r = b & 3;
    tokB[(blk*SS + s)*4 + r] = inp[b*SS + s];
  }
  if (idx < 4096){                      // mask bit-pack
    int b = idx >> 2, seg = idx & 3;
    unsigned long long bits = 0ull;
    int base = b * SS + seg * 64;
    int n = (seg < 3) ? 64 : (SS - 192);
    for (int i = 0; i < n; ++i)
      if (inp[base + i] != 0) bits |= (1ull << i);
    maskP[idx] = bits;
  }
  // emb -> bf16 B-frags for logits (6252*1024 elems)
  for (int i = idx; i < 6402048; i += 262144){
    int j = i & 7, lane = (i >> 3) & 63, kt = (i >> 9) & 1, vt = i >> 10;
    int col = lane & 15, hi = lane >> 4;
    int v = vt*16 + col, k = kt*32 + hi*8 + j;
    float val = (v < NV) ? emb[(size_t)v*64 + k] : 0.f;
    ebf[i] = f2bf(val);
  }
}

// ---------------- LSTM: 256 blocks x 1024 thr (16 waves); 4 batch rows per block ----
// Round-12: gates still the wall (per-active-CU VALU ~68% at 128 CUs). 256 blocks
// (every CU), 4-way lane-spread: groups l15/4 pull reg (l15>>2) from src lane
// (lane&48)|bcol via ds_bpermute -> each thread owns ONE (b,u) with all 4 gates:
// 5 sigm/thread (was 10). Weights unchanged (i8 A-frags resident).
// LDS: h 2x4096 (canonical layout, cols 0-3 live) | x 3x1024 | tok 3200 = 14464 B
__global__ void __attribute__((amdgpu_flat_work_group_size(1024, 1024),
                               amdgpu_waves_per_eu(4, 4)))
lstm_kernel(const float* __restrict__ emb,
            const float* __restrict__ bias,
            const char* __restrict__ rq,
            const char* __restrict__ kq,
            const int* __restrict__ tokB,
            const unsigned long long* __restrict__ maskP,
            const int* __restrict__ sc,
            float* __restrict__ hout){
  extern __shared__ char smem[];
  char* const hbuf = smem;                    // 2 x 4096
  char* const xbuf = smem + 8192;             // 3 x 1024
  int*  const tokL = (int*)(smem + 11264);    // 3200
  const int tid  = threadIdx.x;
  const int lane = tid & 63;
  const int wv   = tid >> 6;       // 0..15
  const int w    = wv >> 1;
  const int hh   = wv & 1;
  const int l15  = lane & 15;
  const int l4   = lane >> 4;
  const int blk  = blockIdx.x;
  const int b0   = blk << 2;       // 4 batch rows per block
  const int bcol = l15 & 3;
  const int grp  = l15 >> 2;
  const int srcb = (((lane & 48) | bcol) << 2);   // bpermute byte addr

  const float maxr = __int_as_float(sc[0]);
  const float maxk = __int_as_float(sc[1]);
  const float S      = maxr * (1.f/16129.f);
  const float SL     = -1.44269504f * S;          // fold -log2e into scale
  const float inv_sx = 127.f * maxk / maxr;

  // ---- prologue staging ----
  if (tid < 800) tokL[tid] = tokB[blk*800 + tid];
  *(int*)(hbuf + tid*4) = 0;                      // zero h parity-0 (4096 B)

  // this thread's single (b,u): b = bcol, u below
  const int u = w*32 + hh*16 + (l4 << 2) + grp;
  float bn[4];
  #pragma unroll
  for (int gg = 0; gg < 4; ++gg) bn[gg] = -1.44269504f * bias[gg*256 + u];

  // resident rec frags (64 VGPR) + kernel frags (16 VGPR)
  int4v Wr[4][4];
  #pragma unroll
  for (int ktt = 0; ktt < 4; ++ktt)
    #pragma unroll
    for (int gg = 0; gg < 4; ++gg)
      Wr[ktt][gg] = *(const int4v*)(rq + ((((w*8 + gg*2+hh)*4 + ktt)) << 10) + (lane << 4));
  int4v Wx[4];
  #pragma unroll
  for (int gg = 0; gg < 4; ++gg)
    Wx[gg] = *(const int4v*)(kq + ((w*8 + gg*2+hh) << 10) + (lane << 4));

  // x staging: waves 0-3 stage batch row wv; elem e = lane
  const int x_wrb = ((lane >> 4) << 8) + (wv << 4) + l15;   // hi*256 + b*16 + j
  float xvP = 0.f;
  if (wv < 4){
    int t0 = tokL[wv];
    *(char*)(xbuf + x_wrb) = (char)q8(emb[(size_t)t0*64 + lane], inv_sx);
    int t1 = tokL[4 + wv];
    *(char*)(xbuf + 1024 + x_wrb) = (char)q8(emb[(size_t)t1*64 + lane], inv_sx);
    int t2 = tokL[8 + wv];
    xvP = emb[(size_t)t2*64 + lane];
  }

  const unsigned long long* maskB = maskP + (size_t)(b0 + bcol) * 4;
  float c = 0.f, hP = 0.f;
  const int f_rd = lane << 4;                    // canonical frag read
  const int h_wb = ((u >> 6) << 10) + (((u >> 4) & 3) << 8) + (bcol << 4) + (u & 15);

  __syncthreads();

  int s = 0, xri = 0;
  #pragma unroll 1
  for (int seg = 0; seg < 4; ++seg){
    unsigned long long cur = maskB[seg];
    const int nn = (seg < 3) ? 64 : (SS - 192);
    #pragma unroll 1
    for (int i = 0; i < nn; ++i, ++s){
      const char* hc = hbuf + ((s & 1) << 12);
      char*       hn = hbuf + (((s & 1) ^ 1) << 12);
      const char* xc = xbuf + xri*1024;
      int xwi = xri + 2; if (xwi >= 3) xwi -= 3;
      char*       xw = xbuf + xwi*1024;

      // stage x(s+2) from register; issue emb(s+3)
      if (wv < 4){
        if (s + 2 < SS) *(char*)(xw + x_wrb) = (char)q8(xvP, inv_sx);
        if (s + 3 < SS){
          int tn = tokL[(s+3)*4 + wv];
          xvP = emb[(size_t)tn*64 + lane];
        }
      }

      // MFMA: x + 4 rec ktt per gate-tile (cols 0-3 valid)
      int4v acc[4];
      #pragma unroll
      for (int gg = 0; gg < 4; ++gg) acc[gg] = int4v{0,0,0,0};
      {
        int4v xf = *(const int4v*)(xc + f_rd);
        #pragma unroll
        for (int gg = 0; gg < 4; ++gg) acc[gg] = MFI(Wx[gg], xf, acc[gg]);
      }
      #pragma unroll
      for (int ktt = 0; ktt < 4; ++ktt){
        int4v hf = *(const int4v*)(hc + (ktt << 10) + f_rd);
        #pragma unroll
        for (int gg = 0; gg < 4; ++gg) acc[gg] = MFI(Wr[ktt][gg], hf, acc[gg]);
      }

      // 4-way lane-spread: group grp takes reg grp from src lane
      float z[4];
      #pragma unroll
      for (int gg = 0; gg < 4; ++gg){
        int t1 = __builtin_amdgcn_ds_bpermute(srcb, acc[gg][1]);
        int t2 = __builtin_amdgcn_ds_bpermute(srcb, acc[gg][2]);
        int t3 = __builtin_amdgcn_ds_bpermute(srcb, acc[gg][3]);
        int zz = (grp == 0) ? acc[gg][0] : (grp == 1) ? t1 : (grp == 2) ? t2 : t3;
        z[gg] = fmaf(SL, (float)zz, bn[gg]);
      }

      // gates: 1 (b,u) per thread, 5 sigm; masked rows keep c,h
      int tkb = (int)(cur & 1ull);
      cur >>= 1;
      {
        float si = sg1(z[0]);
        float sf = sg1(z[1]);
        float sg = sg1(z[2]);
        float so = sg1(z[3]);
        float cn = fmaf(sf, c, si * sg);
        float hv = so * sg1(cn * -1.44269504f);
        if (tkb){ c = cn; hP = hv; }
      }
      *(char*)(hn + h_wb) = (char)(int)rintf(hP * 127.f);   // h in (0,1)

      xri = (xri == 2) ? 0 : xri + 1;
      BAR_LDS();
    }
  }

  // final h (fp32)
  hout[(size_t)(b0 + bcol)*256 + u] = hP;
}

// ---------------- dense: out = h @ dense_w + dense_b; emit bf16 A-frags -------------
// obf layout [bt(64)][kt(2)][lane(64)][j(8)]
__global__ void dense_kernel(const float* __restrict__ h,
                             const float* __restrict__ dw,
                             const float* __restrict__ db,
                             unsigned short* __restrict__ obf){
  int tid = threadIdx.x;
  int e = tid & 63;
  int b = blockIdx.x * 4 + (tid >> 6);
  const float* hb = h + b * 256;
  float a = db[e];
  #pragma unroll 8
  for (int u = 0; u < 256; ++u) a = fmaf(hb[u], dw[u*64 + e], a);
  int bt = b >> 4, row = b & 15, kt = e >> 5, k32 = e & 31;
  int lanea = row + ((k32 >> 3) << 4), jj = k32 & 7;
  obf[(bt*2 + kt)*512 + lanea*8 + jj] = f2bf(a);
}

// ---------------- logits (MFMA bf16): dst = out @ emb.T -----------------------------
// wave: v-group g (64 v = 4 tiles), B-frags resident; loops 32 batch-tiles.
// D: row = batch = (l>>4)*4+r, col = v = l&15  [m89 layout]
__global__ void __launch_bounds__(256)
logits_kernel(const unsigned short* __restrict__ ebf,
              const unsigned short* __restrict__ obf,
              float* __restrict__ dst){
  const int lane = threadIdx.x & 63;
  const int wq   = threadIdx.x >> 6;
  const int g    = blockIdx.x*4 + wq;
  if (g > 1562) return;
  const int bt0  = blockIdx.y << 5;
  const int l15  = lane & 15;
  const int l4   = lane >> 4;

  short8 Bf[4][2];
  #pragma unroll
  for (int t = 0; t < 4; ++t)
    #pragma unroll
    for (int kt = 0; kt < 2; ++kt)
      Bf[t][kt] = *(const short8*)(ebf + (size_t)((g*4 + t)*2 + kt)*512 + lane*8);

  const int v0 = g * 64;
  #pragma unroll 1
  for (int bt = bt0; bt < bt0 + 32; ++bt){
    short8 A0 = *(const short8*)(obf + (bt*2 + 0)*512 + lane*8);
    short8 A1 = *(const short8*)(obf + (bt*2 + 1)*512 + lane*8);
    #pragma unroll
    for (int t = 0; t < 4; ++t){
      f32x4 acc = f32x4{0.f, 0.f, 0.f, 0.f};
      acc = MFB(A0, Bf[t][0], acc);
      acc = MFB(A1, Bf[t][1], acc);
      int v = v0 + t*16 + l15;
      if (v < NV){
        #pragma unroll
        for (int r = 0; r < 4; ++r){
          int b = bt*16 + l4*4 + r;
          dst[(size_t)b * NV + v] = acc[r];
        }
      }
    }
  }
}

extern "C" void kernel_launch(void* const* d_in, const int* in_sizes, int n_in,
                              void* d_out, int out_size, void* d_ws, size_t ws_size,
                              hipStream_t stream){
  const int*   inp  = (const int*)  d_in[0];
  const float* emb  = (const float*)d_in[1];
  const float* kern = (const float*)d_in[2];
  const float* rec  = (const float*)d_in[3];
  const float* bias = (const float*)d_in[4];
  const float* dw   = (const float*)d_in[5];
  const float* db   = (const float*)d_in[6];
  float* dst = (float*)d_out;
  char* ws = (char*)d_ws;

  int*                sc    = (int*)               (ws);            // 8 B (+pad)
  char*               rq    = (char*)              (ws + 4096);     // 262144 B
  char*               kq    = (char*)              (ws + 266240);   // 65536 B
  int*                tokB  = (int*)               (ws + 331776);   // 819200 B
  unsigned long long* maskP = (unsigned long long*)(ws + 1150976);  // 32768 B
  float*              hbuf  = (float*)             (ws + 1183744);  // 1048576 B
  unsigned short*     obf   = (unsigned short*)    (ws + 2232320);  // 131072 B
  unsigned short*     ebf   = (unsigned short*)    (ws + 2363392);  // 12804096 B

  const int SMEM_BYTES = 14464;
  hipFuncSetAttribute((const void*)lstm_kernel,
                      hipFuncAttributeMaxDynamicSharedMemorySize, SMEM_BYTES);

  hipMemsetAsync(sc, 0, 8, stream);
  scale_kernel <<<64, 256, 0, stream>>>(rec, kern, sc);
  prep_kernel  <<<1024, 256, 0, stream>>>(inp, kern, rec, emb, sc, rq, kq, tokB, maskP, ebf);
  lstm_kernel  <<<256, 1024, SMEM_BYTES, stream>>>(emb, bias, rq, kq, tokB, maskP, sc, hbuf);
  dense_kernel <<<256, 256, 0, stream>>>(hbuf, dw, db, obf);
  logits_kernel<<<dim3(391, 2), 256, 0, stream>>>(ebf, obf, dst);
  (void)in_sizes; (void)n_in; (void)out_size; (void)ws_size;
}

// Round 13
// 454.937 us; speedup vs baseline: 1.9773x; 1.0178x over previous
//
#include <hip/hip_runtime.h>
#include <cstdint>
#include <cstddef>

#define SS 200
#define NV 100001   // V+1

using int4v  = __attribute__((ext_vector_type(4))) int;
using f32x4  = __attribute__((ext_vector_type(4))) float;
using short8 = __attribute__((ext_vector_type(8))) short;

__device__ __forceinline__ unsigned short f2bf(float f){
  unsigned int x = __float_as_uint(f);
  x += 0x7fffu + ((x >> 16) & 1u);
  return (unsigned short)(x >> 16);
}
__device__ __forceinline__ int q8(float v, float inv_s){
  float q = rintf(v * inv_s);
  q = fminf(127.f, fmaxf(-127.f, q));
  return (int)q;
}
// sg1(t) = 1/(1+exp2(t));  sigmoid(z) = sg1(-log2e * z)
__device__ __forceinline__ float sg1(float t){
  return __builtin_amdgcn_rcpf(1.0f + exp2f(t));
}

#define MFI(a,b,c) __builtin_amdgcn_mfma_i32_16x16x64_i8((a),(b),(c),0,0,0)
#define MFB(a,b,c) __builtin_amdgcn_mfma_f32_16x16x32_bf16((a),(b),(c),0,0,0)

// LDS-only barrier: orders LDS traffic; leaves global loads in flight.
#define BAR_LDS() do{                                         \
    __builtin_amdgcn_sched_barrier(0);                        \
    asm volatile("s_waitcnt lgkmcnt(0)" ::: "memory");        \
    __builtin_amdgcn_s_barrier();                             \
    __builtin_amdgcn_sched_barrier(0);                        \
  } while(0)

// ---------------- scale: absmax of rec and kernel -> sc[0], sc[1] (float bits) ------
__global__ void scale_kernel(const float* __restrict__ rec,
                             const float* __restrict__ kern,
                             int* __restrict__ sc){
  __shared__ float red[256];
  int tid = threadIdx.x;
  float mr = 0.f, mk = 0.f;
  for (int i = blockIdx.x*256 + tid; i < 262144; i += 65536) mr = fmaxf(mr, fabsf(rec[i]));
  for (int i = blockIdx.x*256 + tid; i <  65536; i += 65536) mk = fmaxf(mk, fabsf(kern[i]));
  red[tid] = mr; __syncthreads();
  for (int o = 128; o > 0; o >>= 1){ if (tid < o) red[tid] = fmaxf(red[tid], red[tid+o]); __syncthreads(); }
  if (tid == 0) atomicMax(sc + 0, __float_as_int(red[0]));
  __syncthreads();
  red[tid] = mk; __syncthreads();
  for (int o = 128; o > 0; o >>= 1){ if (tid < o) red[tid] = fmaxf(red[tid], red[tid+o]); __syncthreads(); }
  if (tid == 0) atomicMax(sc + 1, __float_as_int(red[0]));
}

// ---------------- prep: i8 weight frags + tokens + mask bits + emb bf16 B-frags -----
// rq  : rec i8 A-frags [tile(64)][ktt(4)][lane(64)][j(16)]
// kq  : kern i8 A-frags [tile(64)][lane(64)][j(16)]
// tokB: tokens per lstm-block [blk(256)][s(200)][r(4)]
// maskP: mask bits, 4 x u64 per batch row
// ebf : emb bf16 B-frags [vt(6252)][kt(2)][lane(64)][j(8)]  (v >= NV zero-padded)
__global__ void prep_kernel(const int* __restrict__ inp,
                            const float* __restrict__ kern,
                            const float* __restrict__ rec,
                            const float* __restrict__ emb,
                            const int* __restrict__ sc,
                            char* __restrict__ rq,
                            char* __restrict__ kq,
                            int* __restrict__ tokB,
                            unsigned long long* __restrict__ maskP,
                            unsigned short* __restrict__ ebf){
  int idx = blockIdx.x * 256 + threadIdx.x;
  float maxr = __int_as_float(sc[0]);
  float maxk = __int_as_float(sc[1]);
  if (idx < 262144){                    // rec: 256 x 1024, coalesced read
    int k = idx >> 10, col = idx & 1023;
    int gg = col >> 8, w = (col >> 5) & 7, hh = (col >> 4) & 1, l15 = col & 15;
    int tile = w*8 + gg*2 + hh;
    int ktt = k >> 6, hi = (k >> 4) & 3, j = k & 15;
    int lane = l15 + (hi << 4);
    rq[((tile*4 + ktt) << 10) + lane*16 + j] = (char)q8(rec[idx], 127.f/maxr);
  }
  if (idx < 65536){                     // kernel: 64 x 1024
    int k = idx >> 10, col = idx & 1023;
    int gg = col >> 8, w = (col >> 5) & 7, hh = (col >> 4) & 1, l15 = col & 15;
    int tile = w*8 + gg*2 + hh;
    int hi = (k >> 4) & 3, j = k & 15;
    int lane = l15 + (hi << 4);
    kq[(tile << 10) + lane*16 + j] = (char)q8(kern[idx], 127.f/maxk);
  }
  if (idx < 204800){                    // tokens: [blk][s][r], blk = b>>2
    int s = idx >> 10, b = idx & 1023;
    int blk = b >> 2, r = b & 3;
    tokB[(blk*SS + s)*4 + r] = inp[b*SS + s];
  }
  if (idx < 4096){                      // mask bit-pack
    int b = idx >> 2, seg = idx & 3;
    unsigned long long bits = 0ull;
    int base = b * SS + seg * 64;
    int n = (seg < 3) ? 64 : (SS - 192);
    for (int i = 0; i < n; ++i)
      if (inp[base + i] != 0) bits |= (1ull << i);
    maskP[idx] = bits;
  }
  // emb -> bf16 B-frags for logits (6252*1024 elems)
  for (int i = idx; i < 6402048; i += 262144){
    int j = i & 7, lane = (i >> 3) & 63, kt = (i >> 9) & 1, vt = i >> 10;
    int col = lane & 15, hi = lane >> 4;
    int v = vt*16 + col, k = kt*32 + hi*8 + j;
    float val = (v < NV) ? emb[(size_t)v*64 + k] : 0.f;
    ebf[i] = f2bf(val);
  }
}

// ---------------- LSTM: 256 blocks x 1024 thr (16 waves); 4 batch rows per block ----
// Round-13: 4-step unroll with static h (period-2) / x (period-4) buffers — removes
// all per-step pointer/rotation bookkeeping; persistent zero4 C-operand removes acc
// re-zeroing (16 movs/step). Gate math unchanged: 4-way lane-spread, 5 sigm/thread.
// LDS: h 2x4096 | x 4x1024 | tok 3200 = 15488 B
__global__ void __attribute__((amdgpu_flat_work_group_size(1024, 1024),
                               amdgpu_waves_per_eu(4, 4)))
lstm_kernel(const float* __restrict__ emb,
            const float* __restrict__ bias,
            const char* __restrict__ rq,
            const char* __restrict__ kq,
            const int* __restrict__ tokB,
            const unsigned long long* __restrict__ maskP,
            const int* __restrict__ sc,
            float* __restrict__ hout){
  extern __shared__ char smem[];
  char* const hbuf = smem;                    // 2 x 4096
  char* const xbuf = smem + 8192;             // 4 x 1024
  int*  const tokL = (int*)(smem + 12288);    // 3200
  const int tid  = threadIdx.x;
  const int lane = tid & 63;
  const int wv   = tid >> 6;       // 0..15
  const int w    = wv >> 1;
  const int hh   = wv & 1;
  const int l15  = lane & 15;
  const int l4   = lane >> 4;
  const int blk  = blockIdx.x;
  const int b0   = blk << 2;       // 4 batch rows per block
  const int bcol = l15 & 3;
  const int grp  = l15 >> 2;
  const int srcb = (((lane & 48) | bcol) << 2);   // bpermute byte addr

  const float maxr = __int_as_float(sc[0]);
  const float maxk = __int_as_float(sc[1]);
  const float S      = maxr * (1.f/16129.f);
  const float SL     = -1.44269504f * S;          // fold -log2e into scale
  const float inv_sx = 127.f * maxk / maxr;

  // ---- prologue staging ----
  if (tid < 800) tokL[tid] = tokB[blk*800 + tid];
  *(int*)(hbuf + tid*4) = 0;                      // zero h parity-0 (4096 B)

  // this thread's single (b,u): b = bcol, u below
  const int u = w*32 + hh*16 + (l4 << 2) + grp;
  float bn[4];
  #pragma unroll
  for (int gg = 0; gg < 4; ++gg) bn[gg] = -1.44269504f * bias[gg*256 + u];

  // resident rec frags (64 regs) + kernel frags (16 regs)
  int4v Wr[4][4];
  #pragma unroll
  for (int ktt = 0; ktt < 4; ++ktt)
    #pragma unroll
    for (int gg = 0; gg < 4; ++gg)
      Wr[ktt][gg] = *(const int4v*)(rq + ((((w*8 + gg*2+hh)*4 + ktt)) << 10) + (lane << 4));
  int4v Wx[4];
  #pragma unroll
  for (int gg = 0; gg < 4; ++gg)
    Wx[gg] = *(const int4v*)(kq + ((w*8 + gg*2+hh) << 10) + (lane << 4));

  const int4v zero4 = int4v{0, 0, 0, 0};          // persistent MFMA C-operand

  // x staging: waves 0-3 stage batch row wv; elem e = lane
  const int x_wrb = ((lane >> 4) << 8) + (wv << 4) + l15;   // hi*256 + b*16 + j
  float xvP = 0.f;
  if (wv < 4){
    int t0 = tokL[wv];
    *(char*)(xbuf + x_wrb) = (char)q8(emb[(size_t)t0*64 + lane], inv_sx);
    int t1 = tokL[4 + wv];
    *(char*)(xbuf + 1024 + x_wrb) = (char)q8(emb[(size_t)t1*64 + lane], inv_sx);
    int t2 = tokL[8 + wv];
    xvP = emb[(size_t)t2*64 + lane];
  }

  const unsigned long long* maskB = maskP + (size_t)(b0 + bcol) * 4;
  float c = 0.f, hP = 0.f;
  const int f_rd = lane << 4;                    // canonical frag read
  const int h_wb = ((u >> 6) << 10) + (((u >> 4) & 3) << 8) + (bcol << 4) + (u & 15);

  __syncthreads();

#define STEP(HC, HN, XC, XW, K)                                                 \
  {                                                                             \
    const int sk = s + (K);                                                     \
    if (wv < 4){                                                                \
      if (sk + 2 < SS) *(char*)((XW) + x_wrb) = (char)q8(xvP, inv_sx);          \
      if (sk + 3 < SS){                                                         \
        int tn = tokL[(sk+3)*4 + wv];                                           \
        xvP = emb[(size_t)tn*64 + lane];                                        \
      }                                                                         \
    }                                                                           \
    int4v acc[4];                                                               \
    {                                                                           \
      int4v xf = *(const int4v*)((XC) + f_rd);                                  \
      _Pragma("unroll")                                                         \
      for (int gg = 0; gg < 4; ++gg) acc[gg] = MFI(Wx[gg], xf, zero4);          \
    }                                                                           \
    _Pragma("unroll")                                                           \
    for (int ktt = 0; ktt < 4; ++ktt){                                          \
      int4v hf = *(const int4v*)((HC) + (ktt << 10) + f_rd);                    \
      _Pragma("unroll")                                                         \
      for (int gg = 0; gg < 4; ++gg) acc[gg] = MFI(Wr[ktt][gg], hf, acc[gg]);   \
    }                                                                           \
    float z[4];                                                                 \
    _Pragma("unroll")                                                           \
    for (int gg = 0; gg < 4; ++gg){                                             \
      int t1 = __builtin_amdgcn_ds_bpermute(srcb, acc[gg][1]);                  \
      int t2 = __builtin_amdgcn_ds_bpermute(srcb, acc[gg][2]);                  \
      int t3 = __builtin_amdgcn_ds_bpermute(srcb, acc[gg][3]);                  \
      int zz = (grp == 0) ? acc[gg][0] : (grp == 1) ? t1 : (grp == 2) ? t2 : t3;\
      z[gg] = fmaf(SL, (float)zz, bn[gg]);                                      \
    }                                                                           \
    int tkb = (int)((cur >> (K)) & 1ull);                                       \
    {                                                                           \
      float si = sg1(z[0]);                                                     \
      float sf = sg1(z[1]);                                                     \
      float sg = sg1(z[2]);                                                     \
      float so = sg1(z[3]);                                                     \
      float cn = fmaf(sf, c, si * sg);                                          \
      float hv = so * sg1(cn * -1.44269504f);                                   \
      if (tkb){ c = cn; hP = hv; }                                              \
    }                                                                           \
    *(char*)((HN) + h_wb) = (char)(int)rintf(hP * 127.f);                       \
    BAR_LDS();                                                                  \
  }

  int s = 0;
  #pragma unroll 1
  for (int seg = 0; seg < 4; ++seg){
    unsigned long long cur = maskB[seg];
    const int nn = (seg < 3) ? 64 : (SS - 192);
    #pragma unroll 1
    for (int i = 0; i < nn; i += 4){
      STEP(hbuf,        hbuf + 4096, xbuf,        xbuf + 2048, 0)
      STEP(hbuf + 4096, hbuf,        xbuf + 1024, xbuf + 3072, 1)
      STEP(hbuf,        hbuf + 4096, xbuf + 2048, xbuf,        2)
      STEP(hbuf + 4096, hbuf,        xbuf + 3072, xbuf + 1024, 3)
      cur >>= 4;
      s += 4;
    }
  }
#undef STEP

  // final h (fp32)
  hout[(size_t)(b0 + bcol)*256 + u] = hP;
}

// ---------------- dense: out = h @ dense_w + dense_b; emit bf16 A-frags -------------
// obf layout [bt(64)][kt(2)][lane(64)][j(8)]
__global__ void dense_kernel(const float* __restrict__ h,
                             const float* __restrict__ dw,
                             const float* __restrict__ db,
                             unsigned short* __restrict__ obf){
  int tid = threadIdx.x;
  int e = tid & 63;
  int b = blockIdx.x * 4 + (tid >> 6);
  const float* hb = h + b * 256;
  float a = db[e];
  #pragma unroll 8
  for (int u = 0; u < 256; ++u) a = fmaf(hb[u], dw[u*64 + e], a);
  int bt = b >> 4, row = b & 15, kt = e >> 5, k32 = e & 31;
  int lanea = row + ((k32 >> 3) << 4), jj = k32 & 7;
  obf[(bt*2 + kt)*512 + lanea*8 + jj] = f2bf(a);
}

// ---------------- logits (MFMA bf16): dst = out @ emb.T -----------------------------
// wave: v-group g (64 v = 4 tiles), B-frags resident; loops 32 batch-tiles.
// D: row = batch = (l>>4)*4+r, col = v = l&15  [m89 layout]
__global__ void __launch_bounds__(256)
logits_kernel(const unsigned short* __restrict__ ebf,
              const unsigned short* __restrict__ obf,
              float* __restrict__ dst){
  const int lane = threadIdx.x & 63;
  const int wq   = threadIdx.x >> 6;
  const int g    = blockIdx.x*4 + wq;
  if (g > 1562) return;
  const int bt0  = blockIdx.y << 5;
  const int l15  = lane & 15;
  const int l4   = lane >> 4;

  short8 Bf[4][2];
  #pragma unroll
  for (int t = 0; t < 4; ++t)
    #pragma unroll
    for (int kt = 0; kt < 2; ++kt)
      Bf[t][kt] = *(const short8*)(ebf + (size_t)((g*4 + t)*2 + kt)*512 + lane*8);

  const int v0 = g * 64;
  #pragma unroll 1
  for (int bt = bt0; bt < bt0 + 32; ++bt){
    short8 A0 = *(const short8*)(obf + (bt*2 + 0)*512 + lane*8);
    short8 A1 = *(const short8*)(obf + (bt*2 + 1)*512 + lane*8);
    #pragma unroll
    for (int t = 0; t < 4; ++t){
      f32x4 acc = f32x4{0.f, 0.f, 0.f, 0.f};
      acc = MFB(A0, Bf[t][0], acc);
      acc = MFB(A1, Bf[t][1], acc);
      int v = v0 + t*16 + l15;
      if (v < NV){
        #pragma unroll
        for (int r = 0; r < 4; ++r){
          int b = bt*16 + l4*4 + r;
          dst[(size_t)b * NV + v] = acc[r];
        }
      }
    }
  }
}

extern "C" void kernel_launch(void* const* d_in, const int* in_sizes, int n_in,
                              void* d_out, int out_size, void* d_ws, size_t ws_size,
                              hipStream_t stream){
  const int*   inp  = (const int*)  d_in[0];
  const float* emb  = (const float*)d_in[1];
  const float* kern = (const float*)d_in[2];
  const float* rec  = (const float*)d_in[3];
  const float* bias = (const float*)d_in[4];
  const float* dw   = (const float*)d_in[5];
  const float* db   = (const float*)d_in[6];
  float* dst = (float*)d_out;
  char* ws = (char*)d_ws;

  int*                sc    = (int*)               (ws);            // 8 B (+pad)
  char*               rq    = (char*)              (ws + 4096);     // 262144 B
  char*               kq    = (char*)              (ws + 266240);   // 65536 B
  int*                tokB  = (int*)               (ws + 331776);   // 819200 B
  unsigned long long* maskP = (unsigned long long*)(ws + 1150976);  // 32768 B
  float*              hbuf  = (float*)             (ws + 1183744);  // 1048576 B
  unsigned short*     obf   = (unsigned short*)    (ws + 2232320);  // 131072 B
  unsigned short*     ebf   = (unsigned short*)    (ws + 2363392);  // 12804096 B

  const int SMEM_BYTES = 15488;
  hipFuncSetAttribute((const void*)lstm_kernel,
                      hipFuncAttributeMaxDynamicSharedMemorySize, SMEM_BYTES);

  hipMemsetAsync(sc, 0, 8, stream);
  scale_kernel <<<256, 256, 0, stream>>>(rec, kern, sc);
  prep_kernel  <<<1024, 256, 0, stream>>>(inp, kern, rec, emb, sc, rq, kq, tokB, maskP, ebf);
  lstm_kernel  <<<256, 1024, SMEM_BYTES, stream>>>(emb, bias, rq, kq, tokB, maskP, sc, hbuf);
  dense_kernel <<<256, 256, 0, stream>>>(hbuf, dw, db, obf);
  logits_kernel<<<dim3(391, 2), 256, 0, stream>>>(ebf, obf, dst);
  (void)in_sizes; (void)n_in; (void)out_size; (void)ws_size;
}